// Round 1
// baseline (13.136 us; speedup 1.0000x reference)
//
#include <hip/hip_runtime.h>

#define LOG2E 1.4426950408889634f

// Reduce-scatter round: lanes exchange half their live values with lane^M,
// halving values-per-lane. After 5 rounds (M=1..16) each lane in a 32-group
// holds one fully-summed value at index bitrev5(lane&31).
template<int M, int HALF>
__device__ __forceinline__ void rs_round(float* v, int lane) {
  const bool up = (lane & M) != 0;
#pragma unroll
  for (int i = 0; i < HALF; ++i) {
    float send = up ? v[i] : v[i + HALF];
    float recv = __shfl_xor(send, M, 64);
    v[i] = (up ? v[i + HALF] : v[i]) + recv;
  }
}

__global__ __launch_bounds__(256, 4) void behler_g3_kernel(
    const float* __restrict__ r_ij, const float* __restrict__ r_ik,
    const float* __restrict__ r_jk, const int* __restrict__ mask,
    const float* __restrict__ etas, float* __restrict__ out)
{
  const int tid  = threadIdx.x;
  const int lane = tid & 63;
  const int wave = tid >> 6;            // 4 waves/block, one row per wave
  const int row  = blockIdx.x * 4 + wave;

  // c[e] = -eta[e] * log2(e)  so exp(-eta*r2) = exp2(c[e]*r2)
  float c[8];
#pragma unroll
  for (int e = 0; e < 8; ++e) c[e] = -etas[e] * LOG2E;

  // accumulators G[e][z] flattened: v[e*4+z]
  float v[32];
#pragma unroll
  for (int i = 0; i < 32; ++i) v[i] = 0.0f;

  const size_t base = (size_t)row * 512;
  const float4* pij = (const float4*)(r_ij + base);
  const float4* pik = (const float4*)(r_ik + base);
  const float4* pjk = (const float4*)(r_jk + base);
  const int4*   pm  = (const int4*)(mask + base);

#pragma unroll
  for (int k = 0; k < 2; ++k) {
    const int idx = k * 64 + lane;      // 64 lanes x float4 = 256 triples/iter
    const float4 vij = pij[idx];
    const float4 vik = pik[idx];
    const float4 vjk = pjk[idx];
    const int4   vm  = pm[idx];
#pragma unroll
    for (int u = 0; u < 4; ++u) {
      const float rij = (u == 0) ? vij.x : (u == 1) ? vij.y : (u == 2) ? vij.z : vij.w;
      const float rik = (u == 0) ? vik.x : (u == 1) ? vik.y : (u == 2) ? vik.z : vik.w;
      const float rjk = (u == 0) ? vjk.x : (u == 1) ? vjk.y : (u == 2) ? vjk.z : vjk.w;
      const int   m   = (u == 0) ? vm.x  : (u == 1) ? vm.y  : (u == 2) ? vm.z  : vm.w;

      const float r2  = fmaf(rik, rik, rij * rij);
      const float num = fmaf(-rjk, rjk, r2);
      // cos_t = (r2 - rjk^2) / (2 rij rik)
      const float ct  = (0.5f * num) * __builtin_amdgcn_rcpf(rij * rik);
      const float x   = 1.0f - ct;
      // Behler cutoff: 0.5*(cos(pi*r/6)+1); v_cos takes revolutions -> r/12.
      // Inputs guarantee r in [0.5,5.5] < RC=6, so the r<RC branch is always taken.
      const float fci = __builtin_amdgcn_cosf(rij * (1.0f / 12.0f)) + 1.0f;
      const float fck = __builtin_amdgcn_cosf(rik * (1.0f / 12.0f)) + 1.0f;
      float fcp = 0.25f * fci * fck;
      fcp = (m != 0) ? fcp : 0.0f;      // masking: zero the whole contribution

      // base^zeta, zeta = {1,2,4,16}, by repeated squaring
      const float x2 = x * x, x4 = x2 * x2, x8 = x4 * x4, x16 = x8 * x8;
      const float b0 = x * fcp, b1 = x2 * fcp, b2 = x4 * fcp, b3 = x16 * fcp;

#pragma unroll
      for (int e = 0; e < 8; ++e) {
        const float w = __builtin_amdgcn_exp2f(c[e] * r2);
        v[e * 4 + 0] = fmaf(w, b0, v[e * 4 + 0]);
        v[e * 4 + 1] = fmaf(w, b1, v[e * 4 + 1]);
        v[e * 4 + 2] = fmaf(w, b2, v[e * 4 + 2]);
        v[e * 4 + 3] = fmaf(w, b3, v[e * 4 + 3]);
      }
    }
  }

  // reduce-scatter across the wave: 32 values over 64 lanes
  rs_round<1, 16>(v, lane);
  rs_round<2, 8>(v, lane);
  rs_round<4, 4>(v, lane);
  rs_round<8, 2>(v, lane);
  rs_round<16, 1>(v, lane);
  v[0] += __shfl_xor(v[0], 32, 64);     // merge the two 32-groups

  const int vidx = __brev(lane & 31) >> 27;  // value id this lane holds
  const int e = vidx >> 2;
  const int z = vidx & 3;

  // zetas = {1,2,4,16}: coef1 = 2^(1-z), coef2 = 2^(1+z)
  float coef;
  int aoff;
  if (lane < 32) {
    coef = (z == 0) ? 1.0f : (z == 1) ? 0.5f : (z == 2) ? 0.125f : 3.0517578125e-05f;
    aoff = z;
  } else {
    coef = (z == 0) ? 4.0f : (z == 1) ? 8.0f : (z == 2) ? 32.0f : 131072.0f;
    aoff = 4 + z;
  }
  out[(size_t)row * 64 + e * 8 + aoff] = v[0] * coef;
}

extern "C" void kernel_launch(void* const* d_in, const int* in_sizes, int n_in,
                              void* d_out, int out_size, void* d_ws, size_t ws_size,
                              hipStream_t stream) {
  const float* r_ij = (const float*)d_in[0];
  const float* r_ik = (const float*)d_in[1];
  const float* r_jk = (const float*)d_in[2];
  const int*   mask = (const int*)d_in[3];
  const float* etas = (const float*)d_in[4];
  float* out = (float*)d_out;

  const int rows   = in_sizes[0] / 512;   // B*N = 4096
  const int blocks = rows / 4;            // 4 rows (waves) per block

  behler_g3_kernel<<<blocks, 256, 0, stream>>>(r_ij, r_ik, r_jk, mask, etas, out);
}